// Round 10
// baseline (102.062 us; speedup 1.0000x reference)
//
#include <hip/hip_runtime.h>

#define LSEQ 512
#define NB 64
#define NCHUNK 71  // 71*16 = 1136 >= 512 + 7*80 + 63 = 1135 steps

// lane l-1's value -> lane l (DPP wave_shr:1, pure VALU).
__device__ __forceinline__ float dpp_shr1(float x) {
  return __int_as_float(
      __builtin_amdgcn_update_dpp(0, __float_as_int(x), 0x138, 0xF, 0xF, false));
}
// lane l+1's value -> lane l (DPP wave_shl:1) — rotating injection register.
__device__ __forceinline__ float dpp_shl1(float x) {
  return __int_as_float(
      __builtin_amdgcn_update_dpp(0, __float_as_int(x), 0x130, 0xF, 0xF, false));
}

// One DP cell in the scaled domain (R' = R*C1, inputs pre-scaled by sqrt(C1)):
// v' = (d' + m') - log2( 1 + exp2(m'-med) + exp2(m'-max) ), m' = min3.
// min's exp2 term is exp2(0)=1 -> 2 exp2 + 1 log (8cy trans each) + 3 sort
// VALU. INF preds -> exp2(-INF)=0; all-INF -> NaN only on inactive cells.
__device__ __forceinline__ float cell(float p, float tcur, float r0, float r1,
                                      float vprev) {
  const float diff = p - tcur;
  const float m = fminf(fminf(r0, r1), vprev);     // v_min3
  const float dm = __builtin_fmaf(diff, diff, m);  // d' + m'
  const float md = __builtin_amdgcn_fmed3f(r0, r1, vprev);
  const float mx = fmaxf(fmaxf(r0, r1), vprev);    // v_max3
  const float e = 1.0f + (__builtin_amdgcn_exp2f(m - md) +
                          __builtin_amdgcn_exp2f(m - mx));  // in [1,3]
  return dm - __builtin_amdgcn_logf(e);            // v_log_f32 = log2
}

// One 16-step chunk. Injection data lives in two per-lane registers that
// rotate down one lane per step (wave_shl:1): lane 0's copy is always the
// value it must inject this step. Only 2 ds_read_b32 per chunk (at top);
// live set ~8 scalars + vv[16] -> nothing for the allocator to sink/spill
// (R7-R9: uniform-load staging was repeatedly sunk, VGPR 28-56, putting
// lgkmcnt waits on every step/sub-body).
template <bool FULL>
__device__ __forceinline__ void chunk16(int cbase, const float* tgp,
                                        const float* ringP, float* ringW,
                                        float p, bool is_l0, bool is_wr,
                                        int lane, float& vprev, float& r0,
                                        float& tcur) {
  // lane k (mod 16): tg'[cbase+k] (consumed by lane 0 at step k), and
  // ring slot cbase+1+k (consumed at step k). 4x replication across the wave.
  float tinj = tgp[(cbase + (lane & 15)) & 511];
  float rinj = ringP[(cbase + 1 + (lane & 15)) & 127];
  float vv[16];
#pragma unroll
  for (int u = 0; u < 16; ++u) {
    const float tsh = dpp_shr1(tcur);
    tcur = is_l0 ? tinj : tsh;  // target'[j-1]
    const float vsh = dpp_shr1(vprev);
    const float r1 = is_l0 ? rinj : vsh;  // R'[i-1][j]
    if (u < 15) {                         // rotate injection regs for next step
      tinj = dpp_shl1(tinj);
      rinj = dpp_shl1(rinj);
    }
    const float v = cell(p, tcur, r0, r1, vprev);
    vv[u] = v;
    if (FULL) {
      vprev = v;
    } else {
      const int j = cbase + 1 + u - lane;
      vprev = (((unsigned)(j - 1)) < (unsigned)LSEQ) ? v : vprev;
    }
    r0 = r1;
  }

  if (is_wr) {  // lane 63 bursts its 16 row-bottom values (8x ds_write_b64)
    const int wb = (cbase - 62) & 127;
#pragma unroll
    for (int k = 0; k < 8; ++k) {
      *(float2*)&ringW[(wb + 2 * k) & 127] =
          make_float2(vv[2 * k], vv[2 * k + 1]);
    }
  }
}

// Soft-DTW banded wavefront, one block per batch, 8 waves x 64 lanes.
// Lane l of wave w owns row i = 64w+l+1, column j = s - 80w - l at step s.
// In-wave neighbors via DPP; cross-wave via LDS ring + barrier every 16 steps.
// Ring entry col J (read by wave w in the chunk whose window covers it, after
// that chunk's top barrier) is burst-written by wave w-1 before that barrier
// (write step J+80w-17 <= last step of the prior chunk). Concurrent
// writer-ahead slots are 18..33 columns past the read window (mod-128 gap
// < 128 -> disjoint). Garbage writes for out-of-range columns alias slots
// whose legitimate write happens later but whose read happens later still.
__global__ __launch_bounds__(512) void dtw_band(
    const float* __restrict__ pred, const float* __restrict__ target,
    float* __restrict__ part) {
  const int b = blockIdx.x;
  const int tid = threadIdx.x;
  const int w = tid >> 6;
  const int lane = tid & 63;
  const bool is_l0 = (lane == 0);
  const bool is_wr = (lane == 63) && (w < 7);

  __shared__ float tg[LSEQ];
  __shared__ float rings[8][128];  // row w: bottom row of band w; row 7: INF

  const float SC = 3.79828146f;  // sqrt(C1), C1 = (1/g)*log2(e), g = 0.1
  const float p = pred[b * LSEQ + tid] * SC;
  tg[tid] = target[b * LSEQ + tid] * SC;
  ((float*)rings)[tid] = INFINITY;
  ((float*)rings)[tid + 512] = INFINITY;

  const int lag = w * 80;
  const int cw0 = 5 * w;  // wave-active chunks: [cw0, cw0+35]
  const float* __restrict__ ringP = rings[w == 0 ? 7 : w - 1];
  float* __restrict__ ringW = rings[w];

  float vprev = INFINITY;                   // R'[i][j-1]
  float r0 = (tid == 0) ? 0.0f : INFINITY;  // R'[i-1][j-1]; seed R'[0][0]=0
  float tcur = 0.0f;                        // target'[j-1] (flows down lanes)

  for (int c = 0; c < NCHUNK; ++c) {
    __syncthreads();  // top of chunk c (also orders the init writes at c=0)
    if (c < cw0 || c > cw0 + 35) continue;  // wave-uniform
    const int cbase = 16 * c - lag;         // >= 0 for active chunks
    if (c >= cw0 + 4 && c <= cw0 + 31)
      chunk16<true>(cbase, tg, ringP, ringW, p, is_l0, is_wr, lane, vprev, r0,
                    tcur);
    else
      chunk16<false>(cbase, tg, ringP, ringW, p, is_l0, is_wr, lane, vprev, r0,
                     tcur);
  }

  if (tid == LSEQ - 1) part[b] = vprev * 0.069314718f;  // unscale: * 1/C1
}

__global__ void dtw_reduce(const float* __restrict__ part,
                           float* __restrict__ out) {
  float v = part[threadIdx.x];
#pragma unroll
  for (int o = 32; o > 0; o >>= 1) v += __shfl_down(v, o);
  if (threadIdx.x == 0) out[0] = v * (1.0f / NB);
}

extern "C" void kernel_launch(void* const* d_in, const int* in_sizes, int n_in,
                              void* d_out, int out_size, void* d_ws,
                              size_t ws_size, hipStream_t stream) {
  const float* pred = (const float*)d_in[0];
  const float* target = (const float*)d_in[1];
  float* part = (float*)d_ws;

  dtw_band<<<NB, LSEQ, 0, stream>>>(pred, target, part);
  dtw_reduce<<<1, 64, 0, stream>>>(part, (float*)d_out);
}